// Round 8
// baseline (293.930 us; speedup 1.0000x reference)
//
#include <hip/hip_runtime.h>

// Problem constants
#define NODES  116
#define HEADS  2
#define DH     116
#define HID    256
#define NGRAPH 512
#define NN     (NGRAPH*NODES)    // 59392
#define DEG    8
#define DOUT   (HEADS*DH)        // 232
#define RSTR   136               // fallback parked-tile row stride

typedef short  s8v  __attribute__((ext_vector_type(8)));
typedef float  f4v  __attribute__((ext_vector_type(4)));

static __device__ __forceinline__ float bf2f(unsigned short u) {
    union { unsigned int i; float f; } c; c.i = ((unsigned int)u) << 16; return c.f;
}
static __device__ __forceinline__ unsigned short f2bf(float f) {
    union { float f; unsigned int u; } c; c.f = f;
    unsigned int u = c.u;
    unsigned int r = (u + 0x7FFFu + ((u >> 16) & 1u)) >> 16;   // RNE
    return (unsigned short)r;
}

#define GLD_LDS16(gptr, lptr) \
    __builtin_amdgcn_global_load_lds((const __attribute__((address_space(1))) void*)(gptr), \
                                     (__attribute__((address_space(3))) void*)(lptr), 16, 0, 0)

// ---------------------------------------------------------------------------
// P: wt bf16 [hd(2)][chunk(4)][kb(8)][quad(4)][n(128)][8k]; chunk = Wq,Wk,Wv,Ws
// columns hd*116..+116, transposed, zero-padded n>=116.  (round-0 verified)
// Each (hd,ch,kb) chunk is a contiguous 8 KB B-tile in MFMA b-frag order.
// ---------------------------------------------------------------------------
__global__ __launch_bounds__(256) void prep_w(const float* __restrict__ Wq,
                                              const float* __restrict__ Wk,
                                              const float* __restrict__ Wv,
                                              const float* __restrict__ Ws,
                                              unsigned short* __restrict__ wt)
{
    unsigned int f = blockIdx.x * 256 + threadIdx.x;   // granule id < 32768
    unsigned int n    = f & 127;
    unsigned int quad = (f >> 7) & 3;
    unsigned int kb   = (f >> 9) & 7;
    unsigned int ch   = (f >> 12) & 3;
    unsigned int hd   = f >> 14;
    unsigned short o[8] = {0,0,0,0,0,0,0,0};
    if (n < NODES) {
        unsigned int col = hd * DH + n;
        unsigned int k   = kb * 32 + quad * 8;
        const float* W = (ch == 0) ? Wq : (ch == 1) ? Wk : (ch == 2) ? Wv : Ws;
        #pragma unroll
        for (int i = 0; i < 8; i++)
            o[i] = f2bf(W[(size_t)(k + i) * DOUT + col]);
    }
    *(uint4*)(wt + (size_t)f * 8) = *(const uint4*)o;
}

// ---------------------------------------------------------------------------
// K_GEMM: flat projection GEMM  [59392 x 256] @ [256 x 1024]  -> qkvs bf16.
//   qkvs row layout: [n][nt(8)][128] where nt = hd*4+ch; cols 116..127 are
//   exact zeros (wt pad).  Grid 464 mt x 8 nt (bid = mt*8+nt: natural XCD
//   round-robin gives each XCD one nt strip -> B fully L2-local).
//   256 thr = 4 waves (2x2), wave tile 64x64, acc[4][4] (64 f32).
//   A staged from h f32 via reg-cvt (R2-verified pattern), B via linear
//   global_load_lds (wt chunk == LDS layout); double-buffered, stage-before-
//   compute, ONE __syncthreads per k-step (R4-verified).  Epilogue parks C
//   in LDS (overlaying the dead A/B buffers) then stores coalesced uint4.
//   LDS 32 KB -> 4+ blocks/CU.
// ---------------------------------------------------------------------------
__global__ __launch_bounds__(256, 4) void k_gemm(
    const float* __restrict__ h,
    const unsigned short* __restrict__ wt,
    unsigned short* __restrict__ qkvs)
{
    __shared__ __align__(16) unsigned short lds[16384];   // 32 KB total
    unsigned short* const A0 = lds;            // [q4][row128][8k] els, dbuf
    unsigned short* const B0 = lds + 8192;     // [q4][col128][8k] els, dbuf

    const int bid = blockIdx.x;
    const int mt  = bid >> 3;          // 0..463
    const int nt  = bid & 7;           // 0..7 = hd*4+ch

    const int tid  = threadIdx.x;
    const int w    = tid >> 6;
    const int lane = tid & 63;
    const int l15  = lane & 15;
    const int quad = lane >> 4;
    const int wm2  = w >> 1;           // 0..1 : 64-row band
    const int wn2  = w & 1;            // 0..1 : 64-col band

    // A staging: thread -> (arow = tid>>1, ahalf = tid&1); 16 f32 per k-step
    const int arow  = tid >> 1;
    const int ahalf = tid & 1;
    const float* hrow = h + ((size_t)mt * 128 + arow) * HID + ahalf * 16;
    const int aq = ahalf * 2;          // first of two q-slots written
    // B staging: 512 granules of 16B per k-step; thread stages t and t+256
    const unsigned short* wtb = wt + (size_t)nt * 8 * 4096;

    f4v acc[4][4];
    #pragma unroll
    for (int i = 0; i < 4; i++)
        #pragma unroll
        for (int j = 0; j < 4; j++)
            #pragma unroll
            for (int r = 0; r < 4; r++) acc[i][j][r] = 0.f;

    // ---- prologue: stage kb=0 into buffer 0 ----
    {
        const char* src = (const char*)(wtb);
        GLD_LDS16(src + tid * 16,         (char*)B0 + tid * 16);
        GLD_LDS16(src + (tid + 256) * 16, (char*)B0 + (tid + 256) * 16);
        float4 v0 = *(const float4*)(hrow + 0);
        float4 v1 = *(const float4*)(hrow + 4);
        float4 v2 = *(const float4*)(hrow + 8);
        float4 v3 = *(const float4*)(hrow + 12);
        unsigned short o[16] = { f2bf(v0.x),f2bf(v0.y),f2bf(v0.z),f2bf(v0.w),
                                 f2bf(v1.x),f2bf(v1.y),f2bf(v1.z),f2bf(v1.w),
                                 f2bf(v2.x),f2bf(v2.y),f2bf(v2.z),f2bf(v2.w),
                                 f2bf(v3.x),f2bf(v3.y),f2bf(v3.z),f2bf(v3.w) };
        *(uint4*)(A0 + ((aq    ) * 128 + arow) * 8) = *(const uint4*)(o);
        *(uint4*)(A0 + ((aq + 1) * 128 + arow) * 8) = *(const uint4*)(o + 8);
    }
    __syncthreads();

    // ---- pipelined k-loop ----
    #pragma unroll
    for (int kb = 0; kb < 8; kb++) {
        const int cur = kb & 1;
        const int nxt = cur ^ 1;
        float4 v0, v1, v2, v3;
        if (kb < 7) {
            const char* src = (const char*)(wtb + (size_t)(kb + 1) * 4096);
            GLD_LDS16(src + tid * 16,         (char*)(B0 + nxt * 4096) + tid * 16);
            GLD_LDS16(src + (tid + 256) * 16, (char*)(B0 + nxt * 4096) + (tid + 256) * 16);
            v0 = *(const float4*)(hrow + (kb + 1) * 32);
            v1 = *(const float4*)(hrow + (kb + 1) * 32 + 4);
            v2 = *(const float4*)(hrow + (kb + 1) * 32 + 8);
            v3 = *(const float4*)(hrow + (kb + 1) * 32 + 12);
        }
        const unsigned short* Ac = A0 + cur * 4096;
        const unsigned short* Bc = B0 + cur * 4096;
        s8v a0 = *(const s8v*)(Ac + (quad * 128 + wm2 * 64 +  0 + l15) * 8);
        s8v a1 = *(const s8v*)(Ac + (quad * 128 + wm2 * 64 + 16 + l15) * 8);
        s8v a2 = *(const s8v*)(Ac + (quad * 128 + wm2 * 64 + 32 + l15) * 8);
        s8v a3 = *(const s8v*)(Ac + (quad * 128 + wm2 * 64 + 48 + l15) * 8);
        #pragma unroll
        for (int j = 0; j < 4; j++) {
            s8v bj = *(const s8v*)(Bc + (quad * 128 + wn2 * 64 + j * 16 + l15) * 8);
            acc[0][j] = __builtin_amdgcn_mfma_f32_16x16x32_bf16(a0, bj, acc[0][j], 0, 0, 0);
            acc[1][j] = __builtin_amdgcn_mfma_f32_16x16x32_bf16(a1, bj, acc[1][j], 0, 0, 0);
            acc[2][j] = __builtin_amdgcn_mfma_f32_16x16x32_bf16(a2, bj, acc[2][j], 0, 0, 0);
            acc[3][j] = __builtin_amdgcn_mfma_f32_16x16x32_bf16(a3, bj, acc[3][j], 0, 0, 0);
        }
        if (kb < 7) {
            unsigned short o[16] = { f2bf(v0.x),f2bf(v0.y),f2bf(v0.z),f2bf(v0.w),
                                     f2bf(v1.x),f2bf(v1.y),f2bf(v1.z),f2bf(v1.w),
                                     f2bf(v2.x),f2bf(v2.y),f2bf(v2.z),f2bf(v2.w),
                                     f2bf(v3.x),f2bf(v3.y),f2bf(v3.z),f2bf(v3.w) };
            *(uint4*)(A0 + nxt * 4096 + ((aq    ) * 128 + arow) * 8) = *(const uint4*)(o);
            *(uint4*)(A0 + nxt * 4096 + ((aq + 1) * 128 + arow) * 8) = *(const uint4*)(o + 8);
        }
        __syncthreads();
    }

    // ---- epilogue: park C in LDS (A/B dead), coalesced uint4 store ----
    unsigned short* cp = lds;                  // [128][128] bf16 = 32 KB
    #pragma unroll
    for (int i = 0; i < 4; i++)
        #pragma unroll
        for (int j = 0; j < 4; j++) {
            int col = wn2 * 64 + j * 16 + l15;
            #pragma unroll
            for (int r = 0; r < 4; r++) {
                int row = wm2 * 64 + i * 16 + quad * 4 + r;
                cp[row * 128 + col] = f2bf(acc[i][j][r]);
            }
        }
    __syncthreads();
    const size_t outb = (size_t)mt * 128 * 1024 + (size_t)nt * 128;
    #pragma unroll
    for (int p = 0; p < 8; p++) {
        int gi  = tid + p * 256;               // 0..2047
        int row = gi >> 4;
        int cg  = gi & 15;
        *(uint4*)(qkvs + outb + (size_t)row * 1024 + cg * 8) =
            *(const uint4*)(cp + row * 128 + cg * 8);
    }
}

// ---------------------------------------------------------------------------
// K_SCORE: per-(dst,head) wave.  8-lane group per edge: 116-dim q.k dot
//   (pads 116..127 are exact zeros -> included freely), butterfly softmax
//   across the 8 groups, PV + skip on remapped lanes (dims lane, lane+64),
//   h_proj written IN-PLACE over the s-slot of qkvs (only this wave touches
//   it), row-sum -> psums.  No LDS, no barriers, ~full occupancy.
//   Duplicate edges: per-edge alpha summed in f32 == segment_sum semantics.
// ---------------------------------------------------------------------------
__global__ __launch_bounds__(256) void k_score(
    unsigned short* __restrict__ qkvs,
    const int* __restrict__ eidx,
    float* __restrict__ psums)
{
    const int wgid = blockIdx.x * 4 + (threadIdx.x >> 6);  // 0..118783
    const int dst  = wgid >> 1;
    const int hd   = wgid & 1;
    const int lane = threadIdx.x & 63;
    const int grp  = lane >> 3;
    const int sub  = lane & 7;
    const int g    = dst / NODES;              // wave-uniform
    const int node = dst - g * NODES;

    const int src = eidx[(size_t)dst * DEG + grp];         // global src row
    const unsigned short* qr = qkvs + (size_t)dst * 1024 + hd * 512;
    const unsigned short* kr = qkvs + (size_t)src * 1024 + hd * 512 + 128;

    float d = 0.f;
    #pragma unroll
    for (int t = 0; t < 2; t++) {
        s8v qv = *(const s8v*)(qr + sub * 8 + t * 64);
        s8v kv = *(const s8v*)(kr + sub * 8 + t * 64);
        #pragma unroll
        for (int e = 0; e < 8; e++)
            d += bf2f((unsigned short)qv[e]) * bf2f((unsigned short)kv[e]);
    }
    d += __shfl_xor(d, 1); d += __shfl_xor(d, 2); d += __shfl_xor(d, 4);

    float s = d * 0.09284766908852594f;        // 1/sqrt(116)
    float m = s;
    m = fmaxf(m, __shfl_xor(m, 8));
    m = fmaxf(m, __shfl_xor(m, 16));
    m = fmaxf(m, __shfl_xor(m, 32));
    float ex  = __expf(s - m);
    float sum = ex;
    sum += __shfl_xor(sum, 8); sum += __shfl_xor(sum, 16); sum += __shfl_xor(sum, 32);
    float alpha = ex / sum;

    // PV + skip: lane covers dims {lane, lane+64}
    const int d1ok = (lane + 64) < NODES;
    float acc0 = 0.f, acc1 = 0.f;
    #pragma unroll
    for (int e = 0; e < 8; e++) {
        float ae = __shfl(alpha, e * 8);
        int   se = __shfl(src,   e * 8);
        const unsigned short* vr = qkvs + (size_t)se * 1024 + hd * 512 + 256;
        acc0 += ae * bf2f(vr[lane]);
        if (d1ok) acc1 += ae * bf2f(vr[lane + 64]);
    }
    const size_t sbase = (size_t)dst * 1024 + hd * 512 + 384;
    unsigned short b0 = f2bf(acc0 + bf2f(qkvs[sbase + lane]));
    qkvs[sbase + lane] = b0;                   // h_proj over own s-slot
    float rs = bf2f(b0);
    if (d1ok) {
        unsigned short b1 = f2bf(acc1 + bf2f(qkvs[sbase + lane + 64]));
        qkvs[sbase + lane + 64] = b1;
        rs += bf2f(b1);
    }
    rs += __shfl_xor(rs, 1);  rs += __shfl_xor(rs, 2);  rs += __shfl_xor(rs, 4);
    rs += __shfl_xor(rs, 8);  rs += __shfl_xor(rs, 16); rs += __shfl_xor(rs, 32);
    if (lane == 0)
        psums[((size_t)hd * NGRAPH + g) * NODES + node] = rs;
}

// ---------------------------------------------------------------------------
// K3: per-graph pooling.  Round-0 verified flow; h_proj read from the qkvs
// s-slots (head0 at +384, head1 at +896 within each 1024-el node row).
// ---------------------------------------------------------------------------
__global__ __launch_bounds__(256) void pool_k3(const unsigned short* __restrict__ qkvs,
                                               const float* __restrict__ psums,
                                               float* __restrict__ out_alpha,
                                               float* __restrict__ out_hw)
{
    __shared__ float ew[NODES];
    __shared__ float alph[NODES];
    __shared__ float red[2];

    const int g   = blockIdx.x;
    const int tid = threadIdx.x;

    if (tid < NODES)
        ew[tid] = (psums[(size_t)g * NODES + tid] +
                   psums[((size_t)NGRAPH + g) * NODES + tid]) * (1.0f / DOUT);
    __syncthreads();
    if (tid < 64) {
        float a = ew[tid];
        float b = (tid + 64 < NODES) ? ew[tid + 64] : -1e30f;
        float mm = fmaxf(a, b);
        #pragma unroll
        for (int off = 32; off > 0; off >>= 1) mm = fmaxf(mm, __shfl_down(mm, off));
        if (tid == 0) red[0] = mm;
    }
    __syncthreads();
    if (tid < NODES) ew[tid] = __expf(ew[tid] - red[0]);
    __syncthreads();
    if (tid < 64) {
        float a = ew[tid] + ((tid + 64 < NODES) ? ew[tid + 64] : 0.0f);
        #pragma unroll
        for (int off = 32; off > 0; off >>= 1) a += __shfl_down(a, off);
        if (tid == 0) red[1] = a;
    }
    __syncthreads();
    if (tid < NODES) {
        float al = ew[tid] / red[1];
        alph[tid] = al;
        out_alpha[(size_t)g * NODES + tid] = al;
    }
    __syncthreads();

    for (int f = tid; f < NODES * 58; f += 256) {   // 58 4-el granules per row
        int r  = f / 58;
        int gi = f - r * 58;
        int d  = gi * 4;
        float al = alph[r];
        size_t row = ((size_t)g * NODES + r) * 1024;
        size_t off = (d < DH) ? (size_t)(384 + d) : (size_t)(896 + d - DH);
        uint2 hv = *(const uint2*)(qkvs + row + off);
        float4 o = make_float4(al * bf2f((unsigned short)(hv.x & 0xFFFF)),
                               al * bf2f((unsigned short)(hv.x >> 16)),
                               al * bf2f((unsigned short)(hv.y & 0xFFFF)),
                               al * bf2f((unsigned short)(hv.y >> 16)));
        *(float4*)(out_hw + ((size_t)(g * NODES + r)) * DOUT + d) = o;
    }
}

// ===========================================================================
// FALLBACK (ws too small): round-4 verified monolith, unchanged.
// ===========================================================================
__global__ __launch_bounds__(1024, 4) void fused_all(
    const float* __restrict__ h,
    const unsigned short* __restrict__ wt,
    const int* __restrict__ eidx,
    unsigned short* __restrict__ hp,
    float* __restrict__ out_alpha,
    float* __restrict__ out_hw)
{
    __shared__ __align__(16) unsigned short stA[8*4096];
    __shared__ __align__(16) unsigned short ovl[2*128*RSTR];
    __shared__ int   srcl[NODES*DEG];
    __shared__ float scf[NODES*DEG];
    __shared__ float ps[2][NODES];
    __shared__ float red[2];

    unsigned short* const ql = ovl;
    unsigned short* const kl = ovl + 128 * RSTR;

    const int g   = blockIdx.x;
    const int tid = threadIdx.x;
    const int w    = tid >> 6;
    const int lane = tid & 63;
    const int l15  = lane & 15;
    const int quad = lane >> 4;
    const int wm   = w >> 2;
    const int wn   = w & 3;

    if (tid < NODES * DEG)
        srcl[tid] = eidx[(size_t)g * NODES * DEG + tid] - g * NODES;

    {
        const int am = tid >> 3;
        const int q8 = tid & 7;
        long grow = (long)g * NODES + am;
        if (grow >= NN) grow = NN - 1;
        const float* hrow = h + (size_t)grow * HID + q8 * 4;
        const int aoff = ((q8 >> 1) * 128 + am) * 8 + (q8 & 1) * 4;
        float4 a8[8];
        #pragma unroll
        for (int kb = 0; kb < 8; kb++) a8[kb] = *(const float4*)(hrow + kb * 32);
        #pragma unroll
        for (int kb = 0; kb < 8; kb++) {
            unsigned short o[4] = { f2bf(a8[kb].x), f2bf(a8[kb].y),
                                    f2bf(a8[kb].z), f2bf(a8[kb].w) };
            *(uint2*)(stA + kb * 4096 + aoff) = *(const uint2*)o;
        }
    }

    #pragma unroll
    for (int hd = 0; hd < 2; hd++) {
        const size_t wbase = (size_t)hd * 4 * 8 * 4096;

        f4v accq[2][2], acck[2][2], accv[2][2], accs[2][2];
        #pragma unroll
        for (int i = 0; i < 2; i++)
            #pragma unroll
            for (int j = 0; j < 2; j++)
                #pragma unroll
                for (int r = 0; r < 4; r++) {
                    accq[i][j][r] = 0.f; acck[i][j][r] = 0.f;
                    accv[i][j][r] = 0.f; accs[i][j][r] = 0.f;
                }

        #pragma unroll
        for (int j = 0; j < 2; j++) {
            int c = w * 2 + j;
            int ch = c >> 3, sub = c & 7;
            const unsigned short* src = wt + wbase + ((size_t)(ch * 8)) * 4096 + sub * 512;
            GLD_LDS16((const char*)src + lane * 16, (char*)ovl + c * 1024);
        }
        __syncthreads();

        #pragma unroll
        for (int kb = 0; kb < 8; kb++) {
            const unsigned short* curb = ovl + (kb & 1) * 16384;
            unsigned short* nxtb = ovl + ((kb & 1) ^ 1) * 16384;
            if (kb < 7) {
                #pragma unroll
                for (int j = 0; j < 2; j++) {
                    int c = w * 2 + j;
                    int ch = c >> 3, sub = c & 7;
                    const unsigned short* src = wt + wbase + ((size_t)(ch * 8 + kb + 1)) * 4096 + sub * 512;
                    GLD_LDS16((const char*)src + lane * 16, (char*)nxtb + c * 1024);
                }
            }
            const unsigned short* sa = stA + kb * 4096;
            s8v a0 = *(const s8v*)(sa + (quad * 128 + wm * 32 + l15) * 8);
            s8v a1 = *(const s8v*)(sa + (quad * 128 + wm * 32 + 16 + l15) * 8);
            #define CHUNK_MFMA(ACC, CH) { \
                s8v b0 = *(const s8v*)(curb + (CH) * 4096 + (quad * 128 + wn * 32 + l15) * 8); \
                s8v b1 = *(const s8v*)(curb + (CH) * 4096 + (quad * 128 + wn * 32 + 16 + l15) * 8); \
                ACC[0][0] = __builtin_amdgcn_mfma_f32_16x16x32_bf16(a0, b0, ACC[0][0], 0, 0, 0); \
                ACC[0][1] = __builtin_amdgcn_mfma_f32_16x16x32_bf16(a0, b1, ACC[0][1], 0, 0, 0); \
                ACC[1][0] = __builtin_amdgcn_mfma_f32_16x16x32_bf16(a1, b0, ACC[1][0], 0, 0, 0); \
                ACC[1][1] = __builtin_amdgcn_mfma_f32_16x16x32_bf16(a1, b1, ACC[1][1], 0, 0, 0); }
            CHUNK_MFMA(accq, 0)
            CHUNK_MFMA(acck, 1)
            CHUNK_MFMA(accv, 2)
            CHUNK_MFMA(accs, 3)
            #undef CHUNK_MFMA
            __syncthreads();
        }

        #pragma unroll
        for (int i = 0; i < 2; i++) {
            #pragma unroll
            for (int j = 0; j < 2; j++) {
                int col = wn * 32 + j * 16 + l15;
                #pragma unroll
                for (int r = 0; r < 4; r++) {
                    int row = wm * 32 + i * 16 + quad * 4 + r;
                    ql[row * RSTR + col] = (col < NODES) ? f2bf(accq[i][j][r]) : 0;
                    kl[row * RSTR + col] = (col < NODES) ? f2bf(acck[i][j][r]) : 0;
                }
            }
        }
        __syncthreads();

        f4v sacc[2][2];
        #pragma unroll
        for (int i = 0; i < 2; i++)
            #pragma unroll
            for (int j = 0; j < 2; j++)
                #pragma unroll
                for (int r = 0; r < 4; r++) sacc[i][j][r] = 0.f;
        #pragma unroll
        for (int ks = 0; ks < 4; ks++) {
            s8v a0 = *(const s8v*)(ql + (wm * 32 + l15) * RSTR + ks * 32 + quad * 8);
            s8v a1 = *(const s8v*)(ql + (wm * 32 + 16 + l15) * RSTR + ks * 32 + quad * 8);
            s8v b0 = *(const s8v*)(kl + (wn * 32 + l15) * RSTR + ks * 32 + quad * 8);
            s8v b1 = *(const s8v*)(kl + (wn * 32 + 16 + l15) * RSTR + ks * 32 + quad * 8);
            sacc[0][0] = __builtin_amdgcn_mfma_f32_16x16x32_bf16(a0, b0, sacc[0][0], 0, 0, 0);
            sacc[0][1] = __builtin_amdgcn_mfma_f32_16x16x32_bf16(a0, b1, sacc[0][1], 0, 0, 0);
            sacc[1][0] = __builtin_amdgcn_mfma_f32_16x16x32_bf16(a1, b0, sacc[1][0], 0, 0, 0);
            sacc[1][1] = __builtin_amdgcn_mfma_f32_16x16x32_bf16(a1, b1, sacc[1][1], 0, 0, 0);
        }
        #pragma unroll
        for (int i = 0; i < 2; i++) {
            #pragma unroll
            for (int r = 0; r < 4; r++) {
                int row = wm * 32 + i * 16 + quad * 4 + r;
                if (row < NODES) {
                    #pragma unroll
                    for (int j = 0; j < 2; j++) {
                        int col = wn * 32 + j * 16 + l15;
                        #pragma unroll
                        for (int e = 0; e < DEG; e++)
                            if (srcl[row * DEG + e] == col)
                                scf[row * DEG + e] = sacc[i][j][r];
                    }
                }
            }
        }
        __syncthreads();

        for (int f = tid; f < 128 * RSTR / 8; f += 1024)
            *(uint4*)(kl + (size_t)f * 8) = make_uint4(0u, 0u, 0u, 0u);
        #pragma unroll
        for (int i = 0; i < 2; i++) {
            #pragma unroll
            for (int j = 0; j < 2; j++) {
                int col = wn * 32 + j * 16 + l15;
                #pragma unroll
                for (int r = 0; r < 4; r++) {
                    int row = wm * 32 + i * 16 + quad * 4 + r;
                    ql[col * RSTR + row] = (row < NODES) ? f2bf(accv[i][j][r]) : 0;
                }
            }
        }
        __syncthreads();

        if (tid < NODES * DEG) {
            float s = scf[tid] * 0.09284766908852594f;
            float m = s;
            m = fmaxf(m, __shfl_xor(m, 1));
            m = fmaxf(m, __shfl_xor(m, 2));
            m = fmaxf(m, __shfl_xor(m, 4));
            float e = __expf(s - m);
            float sum = e;
            sum += __shfl_xor(sum, 1);
            sum += __shfl_xor(sum, 2);
            sum += __shfl_xor(sum, 4);
            scf[tid] = e / sum;
        }
        __syncthreads();

        if (tid < NODES) {
            #pragma unroll
            for (int j = 0; j < DEG; j++) {
                int sj = srcl[tid * DEG + j];
                bool first = true;
                for (int jj = 0; jj < j; jj++) first = first && (srcl[tid * DEG + jj] != sj);
                if (first) {
                    float a = scf[tid * DEG + j];
                    for (int jj = j + 1; jj < DEG; jj++)
                        if (srcl[tid * DEG + jj] == sj) a += scf[tid * DEG + jj];
                    kl[tid * RSTR + sj] = f2bf(a);
                }
            }
        }
        __syncthreads();

        #pragma unroll
        for (int ks = 0; ks < 4; ks++) {
            s8v a0 = *(const s8v*)(kl + (wm * 32 + l15) * RSTR + ks * 32 + quad * 8);
            s8v a1 = *(const s8v*)(kl + (wm * 32 + 16 + l15) * RSTR + ks * 32 + quad * 8);
            s8v b0 = *(const s8v*)(ql + (wn * 32 + l15) * RSTR + ks * 32 + quad * 8);
            s8v b1 = *(const s8v*)(ql + (wn * 32 + 16 + l15) * RSTR + ks * 32 + quad * 8);
            accs[0][0] = __builtin_amdgcn_mfma_f32_16x16x32_bf16(a0, b0, accs[0][0], 0, 0, 0);
            accs[0][1] = __builtin_amdgcn_mfma_f32_16x16x32_bf16(a0, b1, accs[0][1], 0, 0, 0);
            accs[1][0] = __builtin_amdgcn_mfma_f32_16x16x32_bf16(a1, b0, accs[1][0], 0, 0, 0);
            accs[1][1] = __builtin_amdgcn_mfma_f32_16x16x32_bf16(a1, b1, accs[1][1], 0, 0, 0);
        }
        __syncthreads();

        #pragma unroll
        for (int i = 0; i < 2; i++) {
            #pragma unroll
            for (int j = 0; j < 2; j++) {
                int col = wn * 32 + j * 16 + l15;
                #pragma unroll
                for (int r = 0; r < 4; r++) {
                    int row = wm * 32 + i * 16 + quad * 4 + r;
                    ql[row * RSTR + col] = f2bf(accs[i][j][r]);
                }
            }
        }
        __syncthreads();

        if (tid < NODES * DEG) {
            const int i   = tid >> 3;
            const int seg = tid & 7;
            float rs = 0.0f;
            #pragma unroll
            for (int t = 0; t < 2; t++) {
                int gi = seg + t * 8;
                if (gi < 15) {
                    const s8v v8 = *(const s8v*)(ql + i * RSTR + gi * 8);
                    #pragma unroll
                    for (int e = 0; e < 8; e++) rs += bf2f((unsigned short)v8[e]);
                }
            }
            rs += __shfl_xor(rs, 1);
            rs += __shfl_xor(rs, 2);
            rs += __shfl_xor(rs, 4);
            if (seg == 0) ps[hd][i] = rs;
        }
        if (hd == 0) {
            for (int f = tid; f < NODES * 29; f += 1024) {
                int r  = f / 29;
                int gi = f - r * 29;
                *(uint2*)(hp + ((size_t)g * NODES + r) * 116 + gi * 4) =
                    *(const uint2*)(ql + r * RSTR + gi * 4);
            }
        }
        __syncthreads();
    }

    if (tid < NODES) scf[tid] = (ps[0][tid] + ps[1][tid]) * (1.0f / DOUT);
    __syncthreads();
    if (tid < 64) {
        float a = scf[tid];
        float b = (tid + 64 < NODES) ? scf[tid + 64] : -1e30f;
        float mm = fmaxf(a, b);
        #pragma unroll
        for (int off = 32; off > 0; off >>= 1) mm = fmaxf(mm, __shfl_down(mm, off));
        if (tid == 0) red[0] = mm;
    }
    __syncthreads();
    if (tid < NODES) scf[tid] = __expf(scf[tid] - red[0]);
    __syncthreads();
    if (tid < 64) {
        float a = scf[tid] + ((tid + 64 < NODES) ? scf[tid + 64] : 0.0f);
        #pragma unroll
        for (int off = 32; off > 0; off >>= 1) a += __shfl_down(a, off);
        if (tid == 0) red[1] = a;
    }
    __syncthreads();
    if (tid < NODES) {
        float al = scf[tid] / red[1];
        scf[tid] = al;
        out_alpha[(size_t)g * NODES + tid] = al;
    }
    __syncthreads();
    for (int f = tid; f < NODES * 58; f += 1024) {
        int r  = f / 58;
        int gi = f - r * 58;
        float al = scf[r];
        float4 o;
        if (gi < 29) {
            uint2 hv = *(const uint2*)(hp + ((size_t)g * NODES + r) * 116 + gi * 4);
            o = make_float4(al * bf2f((unsigned short)(hv.x & 0xFFFF)),
                            al * bf2f((unsigned short)(hv.x >> 16)),
                            al * bf2f((unsigned short)(hv.y & 0xFFFF)),
                            al * bf2f((unsigned short)(hv.y >> 16)));
        } else {
            const unsigned short* hv = ql + r * RSTR + (gi - 29) * 4;
            o = make_float4(al * bf2f(hv[0]), al * bf2f(hv[1]),
                            al * bf2f(hv[2]), al * bf2f(hv[3]));
        }
        *(float4*)(out_hw + ((size_t)g * NODES + r) * DOUT + gi * 4) = o;
    }
}

// ---------------------------------------------------------------------------
extern "C" void kernel_launch(void* const* d_in, const int* in_sizes, int n_in,
                              void* d_out, int out_size, void* d_ws, size_t ws_size,
                              hipStream_t stream)
{
    const float* h    = (const float*)d_in[0];
    const int*   eidx = (const int*)d_in[1];   // row 0 = src
    const float* Wq   = (const float*)d_in[3];
    const float* Wk   = (const float*)d_in[4];
    const float* Wv   = (const float*)d_in[5];
    const float* Ws   = (const float*)d_in[6];

    float* out_alpha = (float*)d_out;          // [512][116]
    float* out_hw    = out_alpha + NN;         // [59392][232]

    // Workspace: wt 0.5MB | qkvs 121.6MB | psums 0.46MB  (~122.6 MB total)
    const size_t WT_ELS   = 262144;
    const size_t QKVS_ELS = (size_t)NN * 1024;           // 60,817,408
    const size_t PS_F32   = (size_t)2 * NGRAPH * NODES;  // 118,784
    const size_t NEED = (WT_ELS + QKVS_ELS) * 2 + PS_F32 * 4;

    unsigned short* wt = (unsigned short*)d_ws;
    prep_w<<<128, 256, 0, stream>>>(Wq, Wk, Wv, Ws, wt);

    if (ws_size >= NEED) {
        unsigned short* qkvs = wt + WT_ELS;
        float*          ps   = (float*)(qkvs + QKVS_ELS);
        k_gemm<<<464 * 8, 256, 0, stream>>>(h, wt, qkvs);
        k_score<<<(NN * 2) / 4, 256, 0, stream>>>(qkvs, eidx, ps);
        pool_k3<<<NGRAPH, 256, 0, stream>>>(qkvs, ps, out_alpha, out_hw);
    } else {
        unsigned short* hp = wt + WT_ELS;                // 13.8 MB (head0 only)
        fused_all<<<NGRAPH, 1024, 0, stream>>>(h, wt, eidx, hp, out_alpha, out_hw);
    }
}

// Round 9
// 262.069 us; speedup vs baseline: 1.1216x; 1.1216x over previous
//
#include <hip/hip_runtime.h>

// Problem constants
#define NODES  116
#define HEADS  2
#define DH     116
#define HID    256
#define NGRAPH 512
#define NN     (NGRAPH*NODES)    // 59392
#define DEG    8
#define DOUT   (HEADS*DH)        // 232
#define RSTR   136               // fallback parked-tile row stride

typedef short  s8v  __attribute__((ext_vector_type(8)));
typedef float  f4v  __attribute__((ext_vector_type(4)));

static __device__ __forceinline__ float bf2f(unsigned short u) {
    union { unsigned int i; float f; } c; c.i = ((unsigned int)u) << 16; return c.f;
}
static __device__ __forceinline__ unsigned short f2bf(float f) {
    union { float f; unsigned int u; } c; c.f = f;
    unsigned int u = c.u;
    unsigned int r = (u + 0x7FFFu + ((u >> 16) & 1u)) >> 16;   // RNE
    return (unsigned short)r;
}

#define GLD_LDS16(gptr, lptr) \
    __builtin_amdgcn_global_load_lds((const __attribute__((address_space(1))) void*)(gptr), \
                                     (__attribute__((address_space(3))) void*)(lptr), 16, 0, 0)

// ---------------------------------------------------------------------------
// P: wt bf16 [hd(2)][chunk(4)][kb(8)][quad(4)][n(128)][8k]; chunk = Wq,Wk,Wv,Ws
// columns hd*116..+116, transposed, zero-padded n>=116.  (round-0 verified)
// ---------------------------------------------------------------------------
__global__ __launch_bounds__(256) void prep_w(const float* __restrict__ Wq,
                                              const float* __restrict__ Wk,
                                              const float* __restrict__ Wv,
                                              const float* __restrict__ Ws,
                                              unsigned short* __restrict__ wt)
{
    unsigned int f = blockIdx.x * 256 + threadIdx.x;   // granule id < 32768
    unsigned int n    = f & 127;
    unsigned int quad = (f >> 7) & 3;
    unsigned int kb   = (f >> 9) & 7;
    unsigned int ch   = (f >> 12) & 3;
    unsigned int hd   = f >> 14;
    unsigned short o[8] = {0,0,0,0,0,0,0,0};
    if (n < NODES) {
        unsigned int col = hd * DH + n;
        unsigned int k   = kb * 32 + quad * 8;
        const float* W = (ch == 0) ? Wq : (ch == 1) ? Wk : (ch == 2) ? Wv : Ws;
        #pragma unroll
        for (int i = 0; i < 8; i++)
            o[i] = f2bf(W[(size_t)(k + i) * DOUT + col]);
    }
    *(uint4*)(wt + (size_t)f * 8) = *(const uint4*)o;
}

// ---------------------------------------------------------------------------
// K_GEMM v2: flat projection GEMM [59392 x 256] @ [256 x 1024] -> qkvs bf16,
//   A-REUSED across all 8 nt within one block (fixes R8's 238 MB h over-fetch
//   from cross-XCD replication: h now fetched exactly once).
//   Grid 928 (mt = 64-row tile), 512 thr = 8 waves (2m x 4n, wave tile 32x32,
//   acc[2][2] = 16 f32).  A (64x256 bf16, 32 KB) staged once from h f32;
//   B read DIRECTLY from global per MFMA (wt = 512 KB, L2-resident per XCD;
//   no staging, no staging barriers).  Per nt: straight-line 8-kb MFMA loop,
//   then C parked in 16 KB LDS -> coalesced uint4 stores.  2 barriers per nt.
//   LDS 48 KB -> 3 blocks/CU.  Arithmetic identical to R8 (same K-order).
// ---------------------------------------------------------------------------
__global__ __launch_bounds__(512, 6) void k_gemm(
    const float* __restrict__ h,
    const unsigned short* __restrict__ wt,
    unsigned short* __restrict__ qkvs)
{
    __shared__ __align__(16) unsigned short stA[8*2048];   // 32 KB  [kb][quad][row64][8k]
    __shared__ __align__(16) unsigned short cpark[64*128]; // 16 KB  C park
    // total 48 KB -> 3 blocks/CU

    const int mt   = blockIdx.x;          // 0..927 (64-row tile)
    const int tid  = threadIdx.x;
    const int w    = tid >> 6;
    const int lane = tid & 63;
    const int l15  = lane & 15;
    const int quad = lane >> 4;
    const int wm3  = w >> 2;              // 0..1 : 32-row band
    const int wn3  = w & 3;               // 0..3 : 32-col band

    // ---- A-fill: h f32 -> bf16 -> stA, once; rows mt*64..+63 (always valid) ----
    {
        const int arow = tid >> 3;        // 0..63
        const int aq8  = tid & 7;
        const float* hrow = h + ((size_t)mt * 64 + arow) * HID + aq8 * 4;
        #pragma unroll
        for (int kb = 0; kb < 8; kb++) {
            float4 av = *(const float4*)(hrow + kb * 32);
            unsigned short o[4] = { f2bf(av.x), f2bf(av.y), f2bf(av.z), f2bf(av.w) };
            *(uint2*)(stA + kb * 2048 + ((aq8 >> 1) * 64 + arow) * 8 + (aq8 & 1) * 4) =
                *(const uint2*)o;
        }
    }
    __syncthreads();

    for (int nt = 0; nt < 8; nt++) {
        const unsigned short* wchb = wt + (size_t)nt * 32768
                                        + (quad * 128 + wn3 * 32 + l15) * 8;
        f4v acc[2][2];
        #pragma unroll
        for (int i = 0; i < 2; i++)
            #pragma unroll
            for (int j = 0; j < 2; j++)
                #pragma unroll
                for (int r = 0; r < 4; r++) acc[i][j][r] = 0.f;

        #pragma unroll
        for (int kb = 0; kb < 8; kb++) {
            const unsigned short* sa = stA + kb * 2048;
            s8v a0 = *(const s8v*)(sa + (quad * 64 + wm3 * 32 + l15) * 8);
            s8v a1 = *(const s8v*)(sa + (quad * 64 + wm3 * 32 + 16 + l15) * 8);
            s8v b0 = *(const s8v*)(wchb + (size_t)kb * 4096);
            s8v b1 = *(const s8v*)(wchb + (size_t)kb * 4096 + 16 * 8);
            acc[0][0] = __builtin_amdgcn_mfma_f32_16x16x32_bf16(a0, b0, acc[0][0], 0, 0, 0);
            acc[0][1] = __builtin_amdgcn_mfma_f32_16x16x32_bf16(a0, b1, acc[0][1], 0, 0, 0);
            acc[1][0] = __builtin_amdgcn_mfma_f32_16x16x32_bf16(a1, b0, acc[1][0], 0, 0, 0);
            acc[1][1] = __builtin_amdgcn_mfma_f32_16x16x32_bf16(a1, b1, acc[1][1], 0, 0, 0);
        }
        // barrier: previous nt's store LDS-reads done before cpark overwrite
        __syncthreads();
        #pragma unroll
        for (int i = 0; i < 2; i++)
            #pragma unroll
            for (int j = 0; j < 2; j++) {
                int col = wn3 * 32 + j * 16 + l15;
                #pragma unroll
                for (int r = 0; r < 4; r++) {
                    int row = wm3 * 32 + i * 16 + quad * 4 + r;
                    cpark[row * 128 + col] = f2bf(acc[i][j][r]);
                }
            }
        __syncthreads();
        // coalesced store: 1024 granules of 16B
        #pragma unroll
        for (int p = 0; p < 2; p++) {
            int gi  = tid + p * 512;
            int row = gi >> 4;
            int cg  = gi & 15;
            *(uint4*)(qkvs + ((size_t)mt * 64 + row) * 1024 + nt * 128 + cg * 8) =
                *(const uint4*)(cpark + row * 128 + cg * 8);
        }
    }
}

// ---------------------------------------------------------------------------
// K_SCORE: per-(dst,head) wave; XCD-AWARE graph mapping (block b -> xcd=b&7
//   serves graphs g == xcd mod 8; all 58 blocks of a graph run back-to-back
//   on ONE XCD -> its 232 KB k/v set stays L2-local; fixes cross-XCD
//   replication).  Body identical to R8-verified: 8-lane group per edge
//   116-dim q.k dot, butterfly softmax, PV + skip (dims lane, lane+64),
//   h_proj in-place over the s-slot, row-sum -> psums.  No LDS, no barriers.
// ---------------------------------------------------------------------------
__global__ __launch_bounds__(256) void k_score(
    unsigned short* __restrict__ qkvs,
    const int* __restrict__ eidx,
    float* __restrict__ psums)
{
    const int b    = blockIdx.x;               // 0..29695
    const int xcd  = b & 7;
    const int iw   = b >> 3;                   // 0..3711
    const int gs   = iw / 58;                  // 0..63
    const int bg   = iw - gs * 58;             // 0..57
    const int g    = gs * 8 + xcd;             // graph 0..511 (bijective)
    const int wl   = bg * 4 + (threadIdx.x >> 6);   // 0..231
    const int node = wl >> 1;
    const int hd   = wl & 1;
    const int dst  = g * NODES + node;
    const int lane = threadIdx.x & 63;
    const int grp  = lane >> 3;
    const int sub  = lane & 7;

    const int src = eidx[(size_t)dst * DEG + grp];         // global src row
    const unsigned short* qr = qkvs + (size_t)dst * 1024 + hd * 512;
    const unsigned short* kr = qkvs + (size_t)src * 1024 + hd * 512 + 128;

    float d = 0.f;
    #pragma unroll
    for (int t = 0; t < 2; t++) {
        s8v qv = *(const s8v*)(qr + sub * 8 + t * 64);
        s8v kv = *(const s8v*)(kr + sub * 8 + t * 64);
        #pragma unroll
        for (int e = 0; e < 8; e++)
            d += bf2f((unsigned short)qv[e]) * bf2f((unsigned short)kv[e]);
    }
    d += __shfl_xor(d, 1); d += __shfl_xor(d, 2); d += __shfl_xor(d, 4);

    float s = d * 0.09284766908852594f;        // 1/sqrt(116)
    float m = s;
    m = fmaxf(m, __shfl_xor(m, 8));
    m = fmaxf(m, __shfl_xor(m, 16));
    m = fmaxf(m, __shfl_xor(m, 32));
    float ex  = __expf(s - m);
    float sum = ex;
    sum += __shfl_xor(sum, 8); sum += __shfl_xor(sum, 16); sum += __shfl_xor(sum, 32);
    float alpha = ex / sum;

    // PV + skip: lane covers dims {lane, lane+64}
    const int d1ok = (lane + 64) < NODES;
    float acc0 = 0.f, acc1 = 0.f;
    #pragma unroll
    for (int e = 0; e < 8; e++) {
        float ae = __shfl(alpha, e * 8);
        int   se = __shfl(src,   e * 8);
        const unsigned short* vr = qkvs + (size_t)se * 1024 + hd * 512 + 256;
        acc0 += ae * bf2f(vr[lane]);
        if (d1ok) acc1 += ae * bf2f(vr[lane + 64]);
    }
    const size_t sbase = (size_t)dst * 1024 + hd * 512 + 384;
    unsigned short b0 = f2bf(acc0 + bf2f(qkvs[sbase + lane]));
    qkvs[sbase + lane] = b0;                   // h_proj over own s-slot
    float rs = bf2f(b0);
    if (d1ok) {
        unsigned short b1 = f2bf(acc1 + bf2f(qkvs[sbase + lane + 64]));
        qkvs[sbase + lane + 64] = b1;
        rs += bf2f(b1);
    }
    rs += __shfl_xor(rs, 1);  rs += __shfl_xor(rs, 2);  rs += __shfl_xor(rs, 4);
    rs += __shfl_xor(rs, 8);  rs += __shfl_xor(rs, 16); rs += __shfl_xor(rs, 32);
    if (lane == 0)
        psums[((size_t)hd * NGRAPH + g) * NODES + node] = rs;
}

// ---------------------------------------------------------------------------
// K3: per-graph pooling (R8-verified).  block g -> XCD g%8, matching where
// k_score left graph g's s-slots in L2.
// ---------------------------------------------------------------------------
__global__ __launch_bounds__(256) void pool_k3(const unsigned short* __restrict__ qkvs,
                                               const float* __restrict__ psums,
                                               float* __restrict__ out_alpha,
                                               float* __restrict__ out_hw)
{
    __shared__ float ew[NODES];
    __shared__ float alph[NODES];
    __shared__ float red[2];

    const int g   = blockIdx.x;
    const int tid = threadIdx.x;

    if (tid < NODES)
        ew[tid] = (psums[(size_t)g * NODES + tid] +
                   psums[((size_t)NGRAPH + g) * NODES + tid]) * (1.0f / DOUT);
    __syncthreads();
    if (tid < 64) {
        float a = ew[tid];
        float b = (tid + 64 < NODES) ? ew[tid + 64] : -1e30f;
        float mm = fmaxf(a, b);
        #pragma unroll
        for (int off = 32; off > 0; off >>= 1) mm = fmaxf(mm, __shfl_down(mm, off));
        if (tid == 0) red[0] = mm;
    }
    __syncthreads();
    if (tid < NODES) ew[tid] = __expf(ew[tid] - red[0]);
    __syncthreads();
    if (tid < 64) {
        float a = ew[tid] + ((tid + 64 < NODES) ? ew[tid + 64] : 0.0f);
        #pragma unroll
        for (int off = 32; off > 0; off >>= 1) a += __shfl_down(a, off);
        if (tid == 0) red[1] = a;
    }
    __syncthreads();
    if (tid < NODES) {
        float al = ew[tid] / red[1];
        alph[tid] = al;
        out_alpha[(size_t)g * NODES + tid] = al;
    }
    __syncthreads();

    for (int f = tid; f < NODES * 58; f += 256) {   // 58 4-el granules per row
        int r  = f / 58;
        int gi = f - r * 58;
        int d  = gi * 4;
        float al = alph[r];
        size_t row = ((size_t)g * NODES + r) * 1024;
        size_t off = (d < DH) ? (size_t)(384 + d) : (size_t)(896 + d - DH);
        uint2 hv = *(const uint2*)(qkvs + row + off);
        float4 o = make_float4(al * bf2f((unsigned short)(hv.x & 0xFFFF)),
                               al * bf2f((unsigned short)(hv.x >> 16)),
                               al * bf2f((unsigned short)(hv.y & 0xFFFF)),
                               al * bf2f((unsigned short)(hv.y >> 16)));
        *(float4*)(out_hw + ((size_t)(g * NODES + r)) * DOUT + d) = o;
    }
}

// ===========================================================================
// FALLBACK (ws too small): round-4 verified monolith, unchanged.
// ===========================================================================
__global__ __launch_bounds__(1024, 4) void fused_all(
    const float* __restrict__ h,
    const unsigned short* __restrict__ wt,
    const int* __restrict__ eidx,
    unsigned short* __restrict__ hp,
    float* __restrict__ out_alpha,
    float* __restrict__ out_hw)
{
    __shared__ __align__(16) unsigned short stA[8*4096];
    __shared__ __align__(16) unsigned short ovl[2*128*RSTR];
    __shared__ int   srcl[NODES*DEG];
    __shared__ float scf[NODES*DEG];
    __shared__ float ps[2][NODES];
    __shared__ float red[2];

    unsigned short* const ql = ovl;
    unsigned short* const kl = ovl + 128 * RSTR;

    const int g   = blockIdx.x;
    const int tid = threadIdx.x;
    const int w    = tid >> 6;
    const int lane = tid & 63;
    const int l15  = lane & 15;
    const int quad = lane >> 4;
    const int wm   = w >> 2;
    const int wn   = w & 3;

    if (tid < NODES * DEG)
        srcl[tid] = eidx[(size_t)g * NODES * DEG + tid] - g * NODES;

    {
        const int am = tid >> 3;
        const int q8 = tid & 7;
        long grow = (long)g * NODES + am;
        if (grow >= NN) grow = NN - 1;
        const float* hrow = h + (size_t)grow * HID + q8 * 4;
        const int aoff = ((q8 >> 1) * 128 + am) * 8 + (q8 & 1) * 4;
        float4 a8[8];
        #pragma unroll
        for (int kb = 0; kb < 8; kb++) a8[kb] = *(const float4*)(hrow + kb * 32);
        #pragma unroll
        for (int kb = 0; kb < 8; kb++) {
            unsigned short o[4] = { f2bf(a8[kb].x), f2bf(a8[kb].y),
                                    f2bf(a8[kb].z), f2bf(a8[kb].w) };
            *(uint2*)(stA + kb * 4096 + aoff) = *(const uint2*)o;
        }
    }

    #pragma unroll
    for (int hd = 0; hd < 2; hd++) {
        const size_t wbase = (size_t)hd * 4 * 8 * 4096;

        f4v accq[2][2], acck[2][2], accv[2][2], accs[2][2];
        #pragma unroll
        for (int i = 0; i < 2; i++)
            #pragma unroll
            for (int j = 0; j < 2; j++)
                #pragma unroll
                for (int r = 0; r < 4; r++) {
                    accq[i][j][r] = 0.f; acck[i][j][r] = 0.f;
                    accv[i][j][r] = 0.f; accs[i][j][r] = 0.f;
                }

        #pragma unroll
        for (int j = 0; j < 2; j++) {
            int c = w * 2 + j;
            int ch = c >> 3, sub = c & 7;
            const unsigned short* src = wt + wbase + ((size_t)(ch * 8)) * 4096 + sub * 512;
            GLD_LDS16((const char*)src + lane * 16, (char*)ovl + c * 1024);
        }
        __syncthreads();

        #pragma unroll
        for (int kb = 0; kb < 8; kb++) {
            const unsigned short* curb = ovl + (kb & 1) * 16384;
            unsigned short* nxtb = ovl + ((kb & 1) ^ 1) * 16384;
            if (kb < 7) {
                #pragma unroll
                for (int j = 0; j < 2; j++) {
                    int c = w * 2 + j;
                    int ch = c >> 3, sub = c & 7;
                    const unsigned short* src = wt + wbase + ((size_t)(ch * 8 + kb + 1)) * 4096 + sub * 512;
                    GLD_LDS16((const char*)src + lane * 16, (char*)nxtb + c * 1024);
                }
            }
            const unsigned short* sa = stA + kb * 4096;
            s8v a0 = *(const s8v*)(sa + (quad * 128 + wm * 32 + l15) * 8);
            s8v a1 = *(const s8v*)(sa + (quad * 128 + wm * 32 + 16 + l15) * 8);
            #define CHUNK_MFMA(ACC, CH) { \
                s8v b0 = *(const s8v*)(curb + (CH) * 4096 + (quad * 128 + wn * 32 + l15) * 8); \
                s8v b1 = *(const s8v*)(curb + (CH) * 4096 + (quad * 128 + wn * 32 + 16 + l15) * 8); \
                ACC[0][0] = __builtin_amdgcn_mfma_f32_16x16x32_bf16(a0, b0, ACC[0][0], 0, 0, 0); \
                ACC[0][1] = __builtin_amdgcn_mfma_f32_16x16x32_bf16(a0, b1, ACC[0][1], 0, 0, 0); \
                ACC[1][0] = __builtin_amdgcn_mfma_f32_16x16x32_bf16(a1, b0, ACC[1][0], 0, 0, 0); \
                ACC[1][1] = __builtin_amdgcn_mfma_f32_16x16x32_bf16(a1, b1, ACC[1][1], 0, 0, 0); }
            CHUNK_MFMA(accq, 0)
            CHUNK_MFMA(acck, 1)
            CHUNK_MFMA(accv, 2)
            CHUNK_MFMA(accs, 3)
            #undef CHUNK_MFMA
            __syncthreads();
        }

        #pragma unroll
        for (int i = 0; i < 2; i++) {
            #pragma unroll
            for (int j = 0; j < 2; j++) {
                int col = wn * 32 + j * 16 + l15;
                #pragma unroll
                for (int r = 0; r < 4; r++) {
                    int row = wm * 32 + i * 16 + quad * 4 + r;
                    ql[row * RSTR + col] = (col < NODES) ? f2bf(accq[i][j][r]) : 0;
                    kl[row * RSTR + col] = (col < NODES) ? f2bf(acck[i][j][r]) : 0;
                }
            }
        }
        __syncthreads();

        f4v sacc[2][2];
        #pragma unroll
        for (int i = 0; i < 2; i++)
            #pragma unroll
            for (int j = 0; j < 2; j++)
                #pragma unroll
                for (int r = 0; r < 4; r++) sacc[i][j][r] = 0.f;
        #pragma unroll
        for (int ks = 0; ks < 4; ks++) {
            s8v a0 = *(const s8v*)(ql + (wm * 32 + l15) * RSTR + ks * 32 + quad * 8);
            s8v a1 = *(const s8v*)(ql + (wm * 32 + 16 + l15) * RSTR + ks * 32 + quad * 8);
            s8v b0 = *(const s8v*)(kl + (wn * 32 + l15) * RSTR + ks * 32 + quad * 8);
            s8v b1 = *(const s8v*)(kl + (wn * 32 + 16 + l15) * RSTR + ks * 32 + quad * 8);
            sacc[0][0] = __builtin_amdgcn_mfma_f32_16x16x32_bf16(a0, b0, sacc[0][0], 0, 0, 0);
            sacc[0][1] = __builtin_amdgcn_mfma_f32_16x16x32_bf16(a0, b1, sacc[0][1], 0, 0, 0);
            sacc[1][0] = __builtin_amdgcn_mfma_f32_16x16x32_bf16(a1, b0, sacc[1][0], 0, 0, 0);
            sacc[1][1] = __builtin_amdgcn_mfma_f32_16x16x32_bf16(a1, b1, sacc[1][1], 0, 0, 0);
        }
        #pragma unroll
        for (int i = 0; i < 2; i++) {
            #pragma unroll
            for (int r = 0; r < 4; r++) {
                int row = wm * 32 + i * 16 + quad * 4 + r;
                if (row < NODES) {
                    #pragma unroll
                    for (int j = 0; j < 2; j++) {
                        int col = wn * 32 + j * 16 + l15;
                        #pragma unroll
                        for (int e = 0; e < DEG; e++)
                            if (srcl[row * DEG + e] == col)
                                scf[row * DEG + e] = sacc[i][j][r];
                    }
                }
            }
        }
        __syncthreads();

        for (int f = tid; f < 128 * RSTR / 8; f += 1024)
            *(uint4*)(kl + (size_t)f * 8) = make_uint4(0u, 0u, 0u, 0u);
        #pragma unroll
        for (int i = 0; i < 2; i++) {
            #pragma unroll
            for (int j = 0; j < 2; j++) {
                int col = wn * 32 + j * 16 + l15;
                #pragma unroll
                for (int r = 0; r < 4; r++) {
                    int row = wm * 32 + i * 16 + quad * 4 + r;
                    ql[col * RSTR + row] = (row < NODES) ? f2bf(accv[i][j][r]) : 0;
                }
            }
        }
        __syncthreads();

        if (tid < NODES * DEG) {
            float s = scf[tid] * 0.09284766908852594f;
            float m = s;
            m = fmaxf(m, __shfl_xor(m, 1));
            m = fmaxf(m, __shfl_xor(m, 2));
            m = fmaxf(m, __shfl_xor(m, 4));
            float e = __expf(s - m);
            float sum = e;
            sum += __shfl_xor(sum, 1);
            sum += __shfl_xor(sum, 2);
            sum += __shfl_xor(sum, 4);
            scf[tid] = e / sum;
        }
        __syncthreads();

        if (tid < NODES) {
            #pragma unroll
            for (int j = 0; j < DEG; j++) {
                int sj = srcl[tid * DEG + j];
                bool first = true;
                for (int jj = 0; jj < j; jj++) first = first && (srcl[tid * DEG + jj] != sj);
                if (first) {
                    float a = scf[tid * DEG + j];
                    for (int jj = j + 1; jj < DEG; jj++)
                        if (srcl[tid * DEG + jj] == sj) a += scf[tid * DEG + jj];
                    kl[tid * RSTR + sj] = f2bf(a);
                }
            }
        }
        __syncthreads();

        #pragma unroll
        for (int ks = 0; ks < 4; ks++) {
            s8v a0 = *(const s8v*)(kl + (wm * 32 + l15) * RSTR + ks * 32 + quad * 8);
            s8v a1 = *(const s8v*)(kl + (wm * 32 + 16 + l15) * RSTR + ks * 32 + quad * 8);
            s8v b0 = *(const s8v*)(ql + (wn * 32 + l15) * RSTR + ks * 32 + quad * 8);
            s8v b1 = *(const s8v*)(ql + (wn * 32 + 16 + l15) * RSTR + ks * 32 + quad * 8);
            accs[0][0] = __builtin_amdgcn_mfma_f32_16x16x32_bf16(a0, b0, accs[0][0], 0, 0, 0);
            accs[0][1] = __builtin_amdgcn_mfma_f32_16x16x32_bf16(a0, b1, accs[0][1], 0, 0, 0);
            accs[1][0] = __builtin_amdgcn_mfma_f32_16x16x32_bf16(a1, b0, accs[1][0], 0, 0, 0);
            accs[1][1] = __builtin_amdgcn_mfma_f32_16x16x32_bf16(a1, b1, accs[1][1], 0, 0, 0);
        }
        __syncthreads();

        #pragma unroll
        for (int i = 0; i < 2; i++) {
            #pragma unroll
            for (int j = 0; j < 2; j++) {
                int col = wn * 32 + j * 16 + l15;
                #pragma unroll
                for (int r = 0; r < 4; r++) {
                    int row = wm * 32 + i * 16 + quad * 4 + r;
                    ql[row * RSTR + col] = f2bf(accs[i][j][r]);
                }
            }
        }
        __syncthreads();

        if (tid < NODES * DEG) {
            const int i   = tid >> 3;
            const int seg = tid & 7;
            float rs = 0.0f;
            #pragma unroll
            for (int t = 0; t < 2; t++) {
                int gi = seg + t * 8;
                if (gi < 15) {
                    const s8v v8 = *(const s8v*)(ql + i * RSTR + gi * 8);
                    #pragma unroll
                    for (int e = 0; e < 8; e++) rs += bf2f((unsigned short)v8[e]);
                }
            }
            rs += __shfl_xor(rs, 1);
            rs += __shfl_xor(rs, 2);
            rs += __shfl_xor(rs, 4);
            if (seg == 0) ps[hd][i] = rs;
        }
        if (hd == 0) {
            for (int f = tid; f < NODES * 29; f += 1024) {
                int r  = f / 29;
                int gi = f - r * 29;
                *(uint2*)(hp + ((size_t)g * NODES + r) * 116 + gi * 4) =
                    *(const uint2*)(ql + r * RSTR + gi * 4);
            }
        }
        __syncthreads();
    }

    if (tid < NODES) scf[tid] = (ps[0][tid] + ps[1][tid]) * (1.0f / DOUT);
    __syncthreads();
    if (tid < 64) {
        float a = scf[tid];
        float b = (tid + 64 < NODES) ? scf[tid + 64] : -1e30f;
        float mm = fmaxf(a, b);
        #pragma unroll
        for (int off = 32; off > 0; off >>= 1) mm = fmaxf(mm, __shfl_down(mm, off));
        if (tid == 0) red[0] = mm;
    }
    __syncthreads();
    if (tid < NODES) scf[tid] = __expf(scf[tid] - red[0]);
    __syncthreads();
    if (tid < 64) {
        float a = scf[tid] + ((tid + 64 < NODES) ? scf[tid + 64] : 0.0f);
        #pragma unroll
        for (int off = 32; off > 0; off >>= 1) a += __shfl_down(a, off);
        if (tid == 0) red[1] = a;
    }
    __syncthreads();
    if (tid < NODES) {
        float al = scf[tid] / red[1];
        scf[tid] = al;
        out_alpha[(size_t)g * NODES + tid] = al;
    }
    __syncthreads();
    for (int f = tid; f < NODES * 58; f += 1024) {
        int r  = f / 58;
        int gi = f - r * 58;
        float al = scf[r];
        float4 o;
        if (gi < 29) {
            uint2 hv = *(const uint2*)(hp + ((size_t)g * NODES + r) * 116 + gi * 4);
            o = make_float4(al * bf2f((unsigned short)(hv.x & 0xFFFF)),
                            al * bf2f((unsigned short)(hv.x >> 16)),
                            al * bf2f((unsigned short)(hv.y & 0xFFFF)),
                            al * bf2f((unsigned short)(hv.y >> 16)));
        } else {
            const unsigned short* hv = ql + r * RSTR + (gi - 29) * 4;
            o = make_float4(al * bf2f(hv[0]), al * bf2f(hv[1]),
                            al * bf2f(hv[2]), al * bf2f(hv[3]));
        }
        *(float4*)(out_hw + ((size_t)g * NODES + r) * DOUT + gi * 4) = o;
    }
}

// ---------------------------------------------------------------------------
extern "C" void kernel_launch(void* const* d_in, const int* in_sizes, int n_in,
                              void* d_out, int out_size, void* d_ws, size_t ws_size,
                              hipStream_t stream)
{
    const float* h    = (const float*)d_in[0];
    const int*   eidx = (const int*)d_in[1];   // row 0 = src
    const float* Wq   = (const float*)d_in[3];
    const float* Wk   = (const float*)d_in[4];
    const float* Wv   = (const float*)d_in[5];
    const float* Ws   = (const float*)d_in[6];

    float* out_alpha = (float*)d_out;          // [512][116]
    float* out_hw    = out_alpha + NN;         // [59392][232]

    // Workspace: wt 0.5MB | qkvs 121.6MB | psums 0.46MB  (~122.6 MB total)
    const size_t WT_ELS   = 262144;
    const size_t QKVS_ELS = (size_t)NN * 1024;           // 60,817,408
    const size_t PS_F32   = (size_t)2 * NGRAPH * NODES;  // 118,784
    const size_t NEED = (WT_ELS + QKVS_ELS) * 2 + PS_F32 * 4;

    unsigned short* wt = (unsigned short*)d_ws;
    prep_w<<<128, 256, 0, stream>>>(Wq, Wk, Wv, Ws, wt);

    if (ws_size >= NEED) {
        unsigned short* qkvs = wt + WT_ELS;
        float*          ps   = (float*)(qkvs + QKVS_ELS);
        k_gemm<<<928, 512, 0, stream>>>(h, wt, qkvs);
        k_score<<<(NN * 2) / 4, 256, 0, stream>>>(qkvs, eidx, ps);
        pool_k3<<<NGRAPH, 256, 0, stream>>>(qkvs, ps, out_alpha, out_hw);
    } else {
        unsigned short* hp = wt + WT_ELS;                // 13.8 MB (head0 only)
        fused_all<<<NGRAPH, 1024, 0, stream>>>(h, wt, eidx, hp, out_alpha, out_hw);
    }
}